// Round 18
// baseline (252.032 us; speedup 1.0000x reference)
//
#include <hip/hip_runtime.h>

// Round 18: re-fused single kernel (d-chain + q-layer + head) with the
// shuffle-free PACKB repack (round 17). Liveness: chain ~110, head ~50 ->
// fits the (256,2)/128-VGPR spill-free operating point. Removes the 50MB
// qsum round-trip, one launch, and per-block head-weight staging.
// Empirical rules baked in: VGPR cap = 256/min_waves_arg; PACKB k-slot
// sigma k=8g+4t+j <-> channel 16t+4g+j with A-tiles CIN-permuted.

typedef _Float16 f16x8 __attribute__((ext_vector_type(8)));
typedef float f32x4 __attribute__((ext_vector_type(4)));
typedef __fp16 fp16x2 __attribute__((ext_vector_type(2)));

#define TILES 50
#define WS_BIAS    12800
#define NBIAS      416

// sigma: B k-slot -> producer channel (within a 32-channel D-tile-pair)
#define CIN(k) (16*(((k)>>2)&1) + 4*((k)>>3) + ((k)&3))

__device__ __forceinline__ float silu_f(float x){
    return x * __builtin_amdgcn_rcpf(1.0f + __expf(-x));
}
__device__ __forceinline__ f32x4 silu4(f32x4 v){
    f32x4 r; r.x=silu_f(v.x); r.y=silu_f(v.y); r.z=silu_f(v.z); r.w=silu_f(v.w);
    return r;
}
__device__ __forceinline__ unsigned pk(float a, float b){
    fp16x2 h = __builtin_amdgcn_cvt_pkrtz(a, b);
    return __builtin_bit_cast(unsigned, h);
}
#define PACKB(RES, T0, T1) {                                                   \
    (RES).x = pk((T0).x,(T0).y); (RES).y = pk((T0).z,(T0).w);                  \
    (RES).z = pk((T1).x,(T1).y); (RES).w = pk((T1).z,(T1).w); }

// ---------------- precompute: composed weights -> A-frag order ----------------

__device__ float l1_Ad0(const float* Wdb, const float* Wtd, int c, int k){
    int h = k>>2, jr = k&3; float a = 0.f;
    for (int i=0;i<32;++i) a += Wdb[64*c+2*i+h]*Wtd[4*i+jr];
    return a;
}
__device__ float l1_AB(const float* Wdb,const float* bdb,const float* btd,int c){
    float b = bdb[c];
    for (int i=0;i<32;++i) b += (Wdb[64*c+2*i]+Wdb[64*c+2*i+1])*btd[i];
    return b;
}
__device__ float l1_M(const float* Wdr,const float* Wtd,int c,int k){
    int h=k>>2, jr=k&3; float a=0.f;
    for(int i=0;i<32;++i) a += Wdr[96*c+3*i+h]*Wtd[4*i+jr];
    return a;
}
__device__ float l1_MB(const float* Wdr,const float* bdr,const float* btd,int c){
    float b = bdr[c];
    for(int i=0;i<32;++i) b += (Wdr[96*c+3*i]+Wdr[96*c+3*i+1])*btd[i];
    return b;
}
__device__ float qn_Q(const float* Wqb, const float* Wtq, int c, int kg){
    int z=kg>>5, kk=kg&31; float a=0.f;
    for(int i=0;i<32;++i) a += Wqb[64*c+2*i+z]*Wtq[32*i+kk];
    return a;
}
__device__ float qn_N(const float* Wqr, const float* Wtq, int c, int kg){
    int z=kg>>5, kk=kg&31; float a=0.f;
    for(int i=0;i<32;++i) a += Wqr[96*c+3*i+z]*Wtq[32*i+kk];
    return a;
}

__global__ void precompute(
    const float* __restrict__ Wtd, const float* __restrict__ btd,
    const float* __restrict__ Wdb, const float* __restrict__ bdb,
    const float* __restrict__ Wdr1, const float* __restrict__ bdr1,
    const float* __restrict__ Wdr2, const float* __restrict__ bdr2,
    const float* __restrict__ Wtq, const float* __restrict__ btq,
    const float* __restrict__ Wqb, const float* __restrict__ bqb,
    const float* __restrict__ Wqr1, const float* __restrict__ bqr1,
    const float* __restrict__ Wqr2, const float* __restrict__ bqr2,
    const float* __restrict__ Wtv, const float* __restrict__ btv,
    const float* __restrict__ Wv1, const float* __restrict__ bv1,
    const float* __restrict__ Wv2, const float* __restrict__ bv2,
    const float* __restrict__ Wvs,
    float* __restrict__ wsf)
{
    const int tid = blockIdx.x*blockDim.x + threadIdx.x;
    const int stride = gridDim.x*blockDim.x;

    for (int it = tid; it < TILES*64; it += stride) {
        const int tile = it >> 6, lane = it & 63;
        const int m = lane & 15, g = lane >> 4;
        float v[8];
        #pragma unroll
        for (int j = 0; j < 8; ++j) {
            const int k = 8*g + j;
            float val = 0.f;
            if (tile < 6) {
                // layer1: B is raw-input Bxi -- NO sigma
                const int r = 16*tile + m;
                if (r < 32) {
                    if (r < 30) {
                        if (k < 8)      val = l1_Ad0(Wdb, Wtd, r, k);
                        else if (k==8)  val = l1_AB(Wdb, bdb, btd, r);
                    } else if (r == 30) val = (k==9)  ? 1.f : 0.f;
                    else                val = (k==10) ? 1.f : 0.f;
                } else {
                    const float* Wdr = (r<64)? Wdr1 : Wdr2;
                    const float* bdr = (r<64)? bdr1 : bdr2;
                    const int c = (r<64)? r-32 : r-64;
                    if (k < 8) {
                        val = l1_M(Wdr, Wtd, c, k);
                        if (c < 30) val += l1_Ad0(Wdb, Wtd, c, k);
                    } else if (k == 8) {
                        val = l1_MB(Wdr, bdr, btd, c);
                        if (c < 30) val += l1_AB(Wdb, bdb, btd, c);
                    } else if (k == 9)  val = (c==30)? 1.f : 0.f;
                    else if (k == 10)   val = (c==31)? 1.f : 0.f;
                }
            } else if (tile < 8)  { val = Wdr1[96*(16*(tile-6)+m) + 3*CIN(k) + 2]; }
            else if (tile < 10)   { val = Wdr2[96*(16*(tile-8)+m) + 3*CIN(k) + 2]; }
            else if (tile < 22) {
                const int tt = tile-10, r = 16*(tt>>1)+m, kg = 32*(tt&1)+CIN(k);
                if (r < 32) { if (r < 30) val = qn_Q(Wqb, Wtq, r, kg); }
                else {
                    const float* Wqr = (r<64)? Wqr1 : Wqr2;
                    const int c = (r<64)? r-32 : r-64;
                    val = qn_N(Wqr, Wtq, c, kg);
                    if (c < 30) val += qn_Q(Wqb, Wtq, c, kg);
                }
            }
            else if (tile < 24)  { val = Wqr1[96*(16*(tile-22)+m) + 3*CIN(k) + 2]; }
            else if (tile < 26)  { val = Wqr2[96*(16*(tile-24)+m) + 3*CIN(k) + 2]; }
            else if (tile < 34) {
                const int tt = tile-26, r = 16*(tt>>1)+m;
                if ((tt&1)==0) val = 0.25f*Wtv[34*r + CIN(k)];
                else {
                    // bias/va K-frag (in-kernel Bva) -- NO sigma
                    if (k==0) val = btv[r];
                    else if (k==1) val = Wtv[34*r+32];
                    else if (k==2) val = Wtv[34*r+33];
                }
            }
            else if (tile < 42) { const int tt=tile-34; val = Wv1[64*(16*(tt>>1)+m) + 32*(tt&1) + CIN(k)]; }
            else                { const int tt=tile-42; val = Wv2[64*(16*(tt>>1)+m) + 32*(tt&1) + CIN(k)]; }
            v[j] = val;
        }
        unsigned* wd = (unsigned*)wsf;
        const int base = tile*256 + lane*4;
        wd[base+0] = pk(v[0],v[1]);
        wd[base+1] = pk(v[2],v[3]);
        wd[base+2] = pk(v[4],v[5]);
        wd[base+3] = pk(v[6],v[7]);
    }

    for (int r = tid; r < NBIAS; r += stride) {
        float val = 0.f;
        if (r < 96) {
            if (r < 30) {
                float b = bqb[r];
                for (int i=0;i<32;++i) b += (Wqb[64*r+2*i]+Wqb[64*r+2*i+1])*btq[i];
                val = b;
            } else if (r >= 32) {
                const float* Wqr = (r<64)? Wqr1 : Wqr2;
                const float* bqr = (r<64)? bqr1 : bqr2;
                const int c = (r<64)? r-32 : r-64;
                float b = bqr[c];
                for (int i=0;i<32;++i) b += (Wqr[96*c+3*i]+Wqr[96*c+3*i+1])*btq[i];
                if (c < 30) {
                    float qb = bqb[c];
                    for (int i=0;i<32;++i) qb += (Wqb[64*c+2*i]+Wqb[64*c+2*i+1])*btq[i];
                    b += qb;
                }
                val = b;
            }
        }
        else if (r < 160) val = bv1[r-96];
        else if (r < 224) val = bv2[r-160];
        else { const int idx = r-224, lq = idx>>6, row = idx&63; val = Wvs[3*row + lq]; }
        wsf[WS_BIAS + r] = val;
    }
}

// ---------------- fused main kernel ------------------------------------------

__global__ __launch_bounds__(256, 2) void resnet_fused(
    const float* __restrict__ P,  const float* __restrict__ DA,
    const float* __restrict__ QA, const float* __restrict__ VA,
    const float* __restrict__ wsf, const float* __restrict__ bvs,
    float* __restrict__ out, int n_total)
{
    __shared__ uint4 lw[TILES*64];
    __shared__ alignas(16) float fb[NBIAS];

    {
        const uint4* src = (const uint4*)wsf;
        for (int i = threadIdx.x; i < TILES*64; i += blockDim.x) lw[i] = src[i];
        uint4* fb4 = (uint4*)fb;
        for (int i = threadIdx.x; i < NBIAS/4; i += blockDim.x) fb4[i] = src[3200 + i];
    }
    __syncthreads();

    const int l  = threadIdx.x & 63;
    const int wv = threadIdx.x >> 6;
    const int c  = l & 15, g = l >> 4;
    const int s  = blockIdx.x*64 + wv*16 + c;
    const int sl = (s < n_total) ? s : (n_total-1);
    const bool g0 = (g==0), g1 = (g==1);

    const uint4* lwl = lw + l;
    #define LDA(T) __builtin_bit_cast(f16x8, lwl[(T)*64])
    #define MFMA(A,B,C) __builtin_amdgcn_mfma_f32_16x16x32_f16((A), __builtin_bit_cast(f16x8,(B)), (C), 0, 0, 0)

    const unsigned me = g0 ? 0x80000000u : 0u;   // eta sign slots
    const unsigned mp = g0 ? 0x00008000u : 0u;   // phi sign slots

    uint4 Bva; Bva.x=0; Bva.y=0; Bva.z=0; Bva.w=0;
    if (g0) {
        const float va0 = VA[2*sl], va1 = VA[2*sl+1];
        Bva.x = pk(1.0f, va0); Bva.y = pk(va1, 0.0f);
    }

    const f32x4 z4 = {0.f,0.f,0.f,0.f};
    float out_acc = 0.0f;

    #pragma unroll 1
    for (int lq = 0; lq < 3; ++lq) {
        uint4 xb[2];
        #pragma unroll
        for (int t = 0; t < 2; ++t) {
            const int pos = 4*lq + 2*t;
            float f0 = P[48*sl + pos],        f1 = P[48*sl + 12 + pos];
            float y0 = P[48*sl + 24 + pos] + 1.0f; y0 -= 2.0f*floorf(y0*0.5f);
            float f2 = y0 - 1.0f,             f3 = P[48*sl + 36 + pos];
            float f4 = P[48*sl + pos + 1],    f5 = P[48*sl + 12 + pos + 1];
            float y1 = P[48*sl + 24 + pos + 1] + 1.0f; y1 -= 2.0f*floorf(y1*0.5f);
            float f6 = y1 - 1.0f,             f7 = P[48*sl + 36 + pos + 1];
            float da0 = DA[12*sl + 2*lq + t];
            float da1 = DA[12*sl + 6 + 2*lq + t];
            uint4 xv; xv.x=0; xv.y=0; xv.z=0; xv.w=0;
            if (g0)      { xv.x = pk(f0,f1); xv.y = pk(f2,f3); xv.z = pk(f4,f5); xv.w = pk(f6,f7); }
            else if (g1) { xv.x = pk(1.0f, da0); xv.y = pk(da1, 0.0f); }
            xb[t] = xv;
        }
        const float qa30m = (g==3) ? QA[6*sl + lq]     : 0.0f;
        const float qa31m = (g==3) ? QA[6*sl + 3 + lq] : 0.0f;

        f32x4 qav0 = z4, qav1 = z4;

        #pragma unroll 1
        for (int var = 0; var < 4; ++var) {
            const unsigned fe = (var>=2)? me : 0u;
            const unsigned fp = (var==1||var==2)? mp : 0u;

            uint4 Bs[2];
            #pragma unroll
            for (int t = 0; t < 2; ++t) {
                uint4 Bxi;
                Bxi.x = xb[t].x ^ fe; Bxi.y = xb[t].y ^ fp;
                Bxi.z = xb[t].z ^ fe; Bxi.w = xb[t].w ^ fp;

                f32x4 a0 = MFMA(LDA(0), Bxi, z4);
                f32x4 a1 = MFMA(LDA(1), Bxi, z4);
                f32x4 a2 = MFMA(LDA(2), Bxi, z4);
                f32x4 a3 = MFMA(LDA(3), Bxi, z4);
                f32x4 a4 = MFMA(LDA(4), Bxi, z4);
                f32x4 a5 = MFMA(LDA(5), Bxi, z4);

                uint4 Bt;
                { f32x4 s0=silu4(a0), s1=silu4(a1); PACKB(Bt, s0, s1); }
                a2 = MFMA(LDA(6), Bt, a2);
                a3 = MFMA(LDA(7), Bt, a3);
                { f32x4 s0=silu4(a2), s1=silu4(a3); PACKB(Bt, s0, s1); }
                a4 = MFMA(LDA(8), Bt, a4);
                a5 = MFMA(LDA(9), Bt, a5);
                { f32x4 s0=silu4(a4), s1=silu4(a5); PACKB(Bs[t], s0, s1); }
            }

            f32x4 q[6];
            #pragma unroll
            for (int mt=0; mt<6; ++mt) {
                f32x4 acc = MFMA(LDA(10+2*mt), Bs[0], *(const f32x4*)&fb[16*mt + 4*g]);
                q[mt] = MFMA(LDA(10+2*mt+1), Bs[1], acc);
            }
            q[1].z += qa30m; q[1].w += qa31m;
            q[3].z += qa30m; q[3].w += qa31m;
            q[5].z += qa30m; q[5].w += qa31m;

            uint4 Bq;
            { f32x4 s0=silu4(q[0]), s1=silu4(q[1]); PACKB(Bq, s0, s1); }
            q[2] = MFMA(LDA(22), Bq, q[2]);
            q[3] = MFMA(LDA(23), Bq, q[3]);
            { f32x4 s0=silu4(q[2]), s1=silu4(q[3]); PACKB(Bq, s0, s1); }
            q[4] = MFMA(LDA(24), Bq, q[4]);
            q[5] = MFMA(LDA(25), Bq, q[5]);
            qav0 += silu4(q[4]);
            qav1 += silu4(q[5]);
        } // var

        // ---- head (fused; BQ straight from qav under sigma) ----
        uint4 BQ; PACKB(BQ, qav0, qav1);
        f32x4 uacc[4], w[4];
        #pragma unroll
        for (int mt=0; mt<4; ++mt) {
            f32x4 acc = MFMA(LDA(26+2*mt), BQ, z4);
            uacc[mt] = MFMA(LDA(27+2*mt), Bva, acc);
        }
        uint4 B0, B1;
        { f32x4 t0=silu4(uacc[0]), t1=silu4(uacc[1]); PACKB(B0, t0, t1); }
        { f32x4 t0=silu4(uacc[2]), t1=silu4(uacc[3]); PACKB(B1, t0, t1); }
        #pragma unroll
        for (int mt=0; mt<4; ++mt) {
            f32x4 acc = MFMA(LDA(34+2*mt), B0, uacc[mt]);   // v1: C = u0
            acc = MFMA(LDA(35+2*mt), B1, acc);
            w[mt] = acc + *(const f32x4*)&fb[96 + 16*mt + 4*g];
        }
        { f32x4 t0=silu4(w[0]), t1=silu4(w[1]); PACKB(B0, t0, t1); }
        { f32x4 t0=silu4(w[2]), t1=silu4(w[3]); PACKB(B1, t0, t1); }
        #pragma unroll
        for (int mt=0; mt<4; ++mt) {
            f32x4 acc = MFMA(LDA(42+2*mt), B0, uacc[mt]);   // v2: C = u0
            acc = MFMA(LDA(43+2*mt), B1, acc);
            w[mt] = acc + *(const f32x4*)&fb[160 + 16*mt + 4*g];
        }
        #pragma unroll
        for (int mt=0; mt<4; ++mt) {
            const f32x4 wvs = *(const f32x4*)&fb[224 + 64*lq + 16*mt + 4*g];
            out_acc += wvs.x*silu_f(w[mt].x) + wvs.y*silu_f(w[mt].y)
                     + wvs.z*silu_f(w[mt].z) + wvs.w*silu_f(w[mt].w);
        }
    } // lq

    out_acc += __shfl_xor(out_acc, 16, 64);
    out_acc += __shfl_xor(out_acc, 32, 64);
    if (g == 0 && s < n_total) out[s] = out_acc + bvs[0];
}

extern "C" void kernel_launch(void* const* d_in, const int* in_sizes, int n_in,
                              void* d_out, int out_size, void* d_ws, size_t ws_size,
                              hipStream_t stream)
{
    (void)n_in; (void)ws_size; (void)out_size;
    const float* P   = (const float*)d_in[1];
    const float* DA  = (const float*)d_in[2];
    const float* QA  = (const float*)d_in[3];
    const float* VA  = (const float*)d_in[4];
    const float* Wtd = (const float*)d_in[5];   const float* btd = (const float*)d_in[6];
    const float* Wdb = (const float*)d_in[7];   const float* bdb = (const float*)d_in[8];
    const float* Wdr1= (const float*)d_in[9];   const float* bdr1= (const float*)d_in[10];
    const float* Wdr2= (const float*)d_in[11];  const float* bdr2= (const float*)d_in[12];
    const float* Wtq = (const float*)d_in[13];  const float* btq = (const float*)d_in[14];
    const float* Wqb = (const float*)d_in[15];  const float* bqb = (const float*)d_in[16];
    const float* Wqr1= (const float*)d_in[17];  const float* bqr1= (const float*)d_in[18];
    const float* Wqr2= (const float*)d_in[19];  const float* bqr2= (const float*)d_in[20];
    const float* Wtv = (const float*)d_in[21];  const float* btv = (const float*)d_in[22];
    const float* Wv1 = (const float*)d_in[23];  const float* bv1 = (const float*)d_in[24];
    const float* Wv2 = (const float*)d_in[25];  const float* bv2 = (const float*)d_in[26];
    const float* Wvs = (const float*)d_in[27];  const float* bvs = (const float*)d_in[28];
    float* out = (float*)d_out;

    const int n_total = in_sizes[1] / 48;   // p is [N,4,12]
    float* wsf = (float*)d_ws;

    precompute<<<dim3(64), dim3(256), 0, stream>>>(
        Wtd, btd, Wdb, bdb, Wdr1, bdr1, Wdr2, bdr2,
        Wtq, btq, Wqb, bqb, Wqr1, bqr1, Wqr2, bqr2,
        Wtv, btv, Wv1, bv1, Wv2, bv2, Wvs, wsf);

    const int grid = (n_total + 63) / 64;   // 256 threads = 4 waves x 16 samples
    resnet_fused<<<dim3(grid), dim3(256), 0, stream>>>(
        P, DA, QA, VA, wsf, bvs, out, n_total);
}

// Round 19
// 205.695 us; speedup vs baseline: 1.2253x; 1.2253x over previous
//
#include <hip/hip_runtime.h>

// Round 19: revert to round-17 two-kernel split (fusion spilled: head+chain
// liveness > 128). part1 untouched (136us, spill-free, 0 bank conflicts).
// part2 now DUAL-SAMPLE (2 streams/thread, 32 samples/wave): PACKB dropped its
// per-stream liveness to ~50 VGPR, so 2 streams fit the (256,2)/128 cap ->
// half the waves + 2x ILP on a latency-bound kernel.

typedef _Float16 f16x8 __attribute__((ext_vector_type(8)));
typedef float f32x4 __attribute__((ext_vector_type(4)));
typedef __fp16 fp16x2 __attribute__((ext_vector_type(2)));

#define TILES 50
#define WS_BIAS    12800
#define NBIAS      416
#define QSUM_DW    13216          // dword offset of qsum region in ws

// sigma: B k-slot -> producer channel (within a 32-channel D-tile-pair)
#define CIN(k) (16*(((k)>>2)&1) + 4*((k)>>3) + ((k)&3))

__device__ __forceinline__ float silu_f(float x){
    return x * __builtin_amdgcn_rcpf(1.0f + __expf(-x));
}
__device__ __forceinline__ f32x4 silu4(f32x4 v){
    f32x4 r; r.x=silu_f(v.x); r.y=silu_f(v.y); r.z=silu_f(v.z); r.w=silu_f(v.w);
    return r;
}
__device__ __forceinline__ unsigned pk(float a, float b){
    fp16x2 h = __builtin_amdgcn_cvt_pkrtz(a, b);
    return __builtin_bit_cast(unsigned, h);
}
#define PACKB(RES, T0, T1) {                                                   \
    (RES).x = pk((T0).x,(T0).y); (RES).y = pk((T0).z,(T0).w);                  \
    (RES).z = pk((T1).x,(T1).y); (RES).w = pk((T1).z,(T1).w); }

// ---------------- precompute: composed weights -> A-frag order ----------------

__device__ float l1_Ad0(const float* Wdb, const float* Wtd, int c, int k){
    int h = k>>2, jr = k&3; float a = 0.f;
    for (int i=0;i<32;++i) a += Wdb[64*c+2*i+h]*Wtd[4*i+jr];
    return a;
}
__device__ float l1_AB(const float* Wdb,const float* bdb,const float* btd,int c){
    float b = bdb[c];
    for (int i=0;i<32;++i) b += (Wdb[64*c+2*i]+Wdb[64*c+2*i+1])*btd[i];
    return b;
}
__device__ float l1_M(const float* Wdr,const float* Wtd,int c,int k){
    int h=k>>2, jr=k&3; float a=0.f;
    for(int i=0;i<32;++i) a += Wdr[96*c+3*i+h]*Wtd[4*i+jr];
    return a;
}
__device__ float l1_MB(const float* Wdr,const float* bdr,const float* btd,int c){
    float b = bdr[c];
    for(int i=0;i<32;++i) b += (Wdr[96*c+3*i]+Wdr[96*c+3*i+1])*btd[i];
    return b;
}
__device__ float qn_Q(const float* Wqb, const float* Wtq, int c, int kg){
    int z=kg>>5, kk=kg&31; float a=0.f;
    for(int i=0;i<32;++i) a += Wqb[64*c+2*i+z]*Wtq[32*i+kk];
    return a;
}
__device__ float qn_N(const float* Wqr, const float* Wtq, int c, int kg){
    int z=kg>>5, kk=kg&31; float a=0.f;
    for(int i=0;i<32;++i) a += Wqr[96*c+3*i+z]*Wtq[32*i+kk];
    return a;
}

__global__ void precompute(
    const float* __restrict__ Wtd, const float* __restrict__ btd,
    const float* __restrict__ Wdb, const float* __restrict__ bdb,
    const float* __restrict__ Wdr1, const float* __restrict__ bdr1,
    const float* __restrict__ Wdr2, const float* __restrict__ bdr2,
    const float* __restrict__ Wtq, const float* __restrict__ btq,
    const float* __restrict__ Wqb, const float* __restrict__ bqb,
    const float* __restrict__ Wqr1, const float* __restrict__ bqr1,
    const float* __restrict__ Wqr2, const float* __restrict__ bqr2,
    const float* __restrict__ Wtv, const float* __restrict__ btv,
    const float* __restrict__ Wv1, const float* __restrict__ bv1,
    const float* __restrict__ Wv2, const float* __restrict__ bv2,
    const float* __restrict__ Wvs,
    float* __restrict__ wsf)
{
    const int tid = blockIdx.x*blockDim.x + threadIdx.x;
    const int stride = gridDim.x*blockDim.x;

    for (int it = tid; it < TILES*64; it += stride) {
        const int tile = it >> 6, lane = it & 63;
        const int m = lane & 15, g = lane >> 4;
        float v[8];
        #pragma unroll
        for (int j = 0; j < 8; ++j) {
            const int k = 8*g + j;
            float val = 0.f;
            if (tile < 6) {
                // layer1: B is raw-input Bxi -- NO sigma
                const int r = 16*tile + m;
                if (r < 32) {
                    if (r < 30) {
                        if (k < 8)      val = l1_Ad0(Wdb, Wtd, r, k);
                        else if (k==8)  val = l1_AB(Wdb, bdb, btd, r);
                    } else if (r == 30) val = (k==9)  ? 1.f : 0.f;
                    else                val = (k==10) ? 1.f : 0.f;
                } else {
                    const float* Wdr = (r<64)? Wdr1 : Wdr2;
                    const float* bdr = (r<64)? bdr1 : bdr2;
                    const int c = (r<64)? r-32 : r-64;
                    if (k < 8) {
                        val = l1_M(Wdr, Wtd, c, k);
                        if (c < 30) val += l1_Ad0(Wdb, Wtd, c, k);
                    } else if (k == 8) {
                        val = l1_MB(Wdr, bdr, btd, c);
                        if (c < 30) val += l1_AB(Wdb, bdb, btd, c);
                    } else if (k == 9)  val = (c==30)? 1.f : 0.f;
                    else if (k == 10)   val = (c==31)? 1.f : 0.f;
                }
            } else if (tile < 8)  { val = Wdr1[96*(16*(tile-6)+m) + 3*CIN(k) + 2]; }
            else if (tile < 10)   { val = Wdr2[96*(16*(tile-8)+m) + 3*CIN(k) + 2]; }
            else if (tile < 22) {
                const int tt = tile-10, r = 16*(tt>>1)+m, kg = 32*(tt&1)+CIN(k);
                if (r < 32) { if (r < 30) val = qn_Q(Wqb, Wtq, r, kg); }
                else {
                    const float* Wqr = (r<64)? Wqr1 : Wqr2;
                    const int c = (r<64)? r-32 : r-64;
                    val = qn_N(Wqr, Wtq, c, kg);
                    if (c < 30) val += qn_Q(Wqb, Wtq, c, kg);
                }
            }
            else if (tile < 24)  { val = Wqr1[96*(16*(tile-22)+m) + 3*CIN(k) + 2]; }
            else if (tile < 26)  { val = Wqr2[96*(16*(tile-24)+m) + 3*CIN(k) + 2]; }
            else if (tile < 34) {
                const int tt = tile-26, r = 16*(tt>>1)+m;
                if ((tt&1)==0) val = 0.25f*Wtv[34*r + CIN(k)];
                else {
                    if (k==0) val = btv[r];
                    else if (k==1) val = Wtv[34*r+32];
                    else if (k==2) val = Wtv[34*r+33];
                }
            }
            else if (tile < 42) { const int tt=tile-34; val = Wv1[64*(16*(tt>>1)+m) + 32*(tt&1) + CIN(k)]; }
            else                { const int tt=tile-42; val = Wv2[64*(16*(tt>>1)+m) + 32*(tt&1) + CIN(k)]; }
            v[j] = val;
        }
        unsigned* wd = (unsigned*)wsf;
        const int base = tile*256 + lane*4;
        wd[base+0] = pk(v[0],v[1]);
        wd[base+1] = pk(v[2],v[3]);
        wd[base+2] = pk(v[4],v[5]);
        wd[base+3] = pk(v[6],v[7]);
    }

    for (int r = tid; r < NBIAS; r += stride) {
        float val = 0.f;
        if (r < 96) {
            if (r < 30) {
                float b = bqb[r];
                for (int i=0;i<32;++i) b += (Wqb[64*r+2*i]+Wqb[64*r+2*i+1])*btq[i];
                val = b;
            } else if (r >= 32) {
                const float* Wqr = (r<64)? Wqr1 : Wqr2;
                const float* bqr = (r<64)? bqr1 : bqr2;
                const int c = (r<64)? r-32 : r-64;
                float b = bqr[c];
                for (int i=0;i<32;++i) b += (Wqr[96*c+3*i]+Wqr[96*c+3*i+1])*btq[i];
                if (c < 30) {
                    float qb = bqb[c];
                    for (int i=0;i<32;++i) qb += (Wqb[64*c+2*i]+Wqb[64*c+2*i+1])*btq[i];
                    b += qb;
                }
                val = b;
            }
        }
        else if (r < 160) val = bv1[r-96];
        else if (r < 224) val = bv2[r-160];
        else { const int idx = r-224, lq = idx>>6, row = idx&63; val = Wvs[3*row + lq]; }
        wsf[WS_BIAS + r] = val;
    }
}

// ---------------- kernel A: d-chain + q-layer -> qsum (packed fp16) ----------

__global__ __launch_bounds__(256, 2) void resnet_part1(
    const float* __restrict__ P,  const float* __restrict__ DA,
    const float* __restrict__ QA, const float* __restrict__ wsf,
    unsigned* __restrict__ qsum, int n_total)
{
    __shared__ uint4 lw[26*64];
    __shared__ alignas(16) float fbA[96];

    {
        const uint4* src = (const uint4*)wsf;
        for (int i = threadIdx.x; i < 26*64; i += blockDim.x) lw[i] = src[i];
        uint4* fb4 = (uint4*)fbA;
        for (int i = threadIdx.x; i < 24; i += blockDim.x) fb4[i] = src[3200 + i];
    }
    __syncthreads();

    const int l  = threadIdx.x & 63;
    const int wv = threadIdx.x >> 6;
    const int c  = l & 15, g = l >> 4;
    const int s  = blockIdx.x*64 + wv*16 + c;
    const int sl = (s < n_total) ? s : (n_total-1);
    const bool g0 = (g==0), g1 = (g==1);

    const uint4* lwl = lw + l;
    #define LDA(T) __builtin_bit_cast(f16x8, lwl[(T)*64])
    #define MFMA(A,B,C) __builtin_amdgcn_mfma_f32_16x16x32_f16((A), __builtin_bit_cast(f16x8,(B)), (C), 0, 0, 0)

    const unsigned me = g0 ? 0x80000000u : 0u;   // eta sign slots
    const unsigned mp = g0 ? 0x00008000u : 0u;   // phi sign slots

    const f32x4 z4 = {0.f,0.f,0.f,0.f};

    #pragma unroll 1
    for (int lq = 0; lq < 3; ++lq) {
        uint4 xb[2];
        #pragma unroll
        for (int t = 0; t < 2; ++t) {
            const int pos = 4*lq + 2*t;
            float f0 = P[48*sl + pos],        f1 = P[48*sl + 12 + pos];
            float y0 = P[48*sl + 24 + pos] + 1.0f; y0 -= 2.0f*floorf(y0*0.5f);
            float f2 = y0 - 1.0f,             f3 = P[48*sl + 36 + pos];
            float f4 = P[48*sl + pos + 1],    f5 = P[48*sl + 12 + pos + 1];
            float y1 = P[48*sl + 24 + pos + 1] + 1.0f; y1 -= 2.0f*floorf(y1*0.5f);
            float f6 = y1 - 1.0f,             f7 = P[48*sl + 36 + pos + 1];
            float da0 = DA[12*sl + 2*lq + t];
            float da1 = DA[12*sl + 6 + 2*lq + t];
            uint4 xv; xv.x=0; xv.y=0; xv.z=0; xv.w=0;
            if (g0)      { xv.x = pk(f0,f1); xv.y = pk(f2,f3); xv.z = pk(f4,f5); xv.w = pk(f6,f7); }
            else if (g1) { xv.x = pk(1.0f, da0); xv.y = pk(da1, 0.0f); }
            xb[t] = xv;
        }
        const float qa30m = (g==3) ? QA[6*sl + lq]     : 0.0f;
        const float qa31m = (g==3) ? QA[6*sl + 3 + lq] : 0.0f;

        f32x4 qav0 = z4, qav1 = z4;

        #pragma unroll 1
        for (int var = 0; var < 4; ++var) {
            const unsigned fe = (var>=2)? me : 0u;
            const unsigned fp = (var==1||var==2)? mp : 0u;

            uint4 Bs[2];
            #pragma unroll
            for (int t = 0; t < 2; ++t) {
                uint4 Bxi;
                Bxi.x = xb[t].x ^ fe; Bxi.y = xb[t].y ^ fp;
                Bxi.z = xb[t].z ^ fe; Bxi.w = xb[t].w ^ fp;

                f32x4 a0 = MFMA(LDA(0), Bxi, z4);
                f32x4 a1 = MFMA(LDA(1), Bxi, z4);
                f32x4 a2 = MFMA(LDA(2), Bxi, z4);
                f32x4 a3 = MFMA(LDA(3), Bxi, z4);
                f32x4 a4 = MFMA(LDA(4), Bxi, z4);
                f32x4 a5 = MFMA(LDA(5), Bxi, z4);

                uint4 Bt;
                { f32x4 s0=silu4(a0), s1=silu4(a1); PACKB(Bt, s0, s1); }
                a2 = MFMA(LDA(6), Bt, a2);
                a3 = MFMA(LDA(7), Bt, a3);
                { f32x4 s0=silu4(a2), s1=silu4(a3); PACKB(Bt, s0, s1); }
                a4 = MFMA(LDA(8), Bt, a4);
                a5 = MFMA(LDA(9), Bt, a5);
                { f32x4 s0=silu4(a4), s1=silu4(a5); PACKB(Bs[t], s0, s1); }
            }

            f32x4 q[6];
            #pragma unroll
            for (int mt=0; mt<6; ++mt) {
                f32x4 acc = MFMA(LDA(10+2*mt), Bs[0], *(const f32x4*)&fbA[16*mt + 4*g]);
                q[mt] = MFMA(LDA(10+2*mt+1), Bs[1], acc);
            }
            q[1].z += qa30m; q[1].w += qa31m;
            q[3].z += qa30m; q[3].w += qa31m;
            q[5].z += qa30m; q[5].w += qa31m;

            uint4 Bq;
            { f32x4 s0=silu4(q[0]), s1=silu4(q[1]); PACKB(Bq, s0, s1); }
            q[2] = MFMA(LDA(22), Bq, q[2]);
            q[3] = MFMA(LDA(23), Bq, q[3]);
            { f32x4 s0=silu4(q[2]), s1=silu4(q[3]); PACKB(Bq, s0, s1); }
            q[4] = MFMA(LDA(24), Bq, q[4]);
            q[5] = MFMA(LDA(25), Bq, q[5]);
            qav0 += silu4(q[4]);
            qav1 += silu4(q[5]);
        } // var

        // qsum: lane(c,g) holds ks 8g..8g+7 directly -> one uint4 store
        if (s < n_total) {
            const int rec = (lq*n_total + sl)*16;
            uint4 w0; PACKB(w0, qav0, qav1);
            *(uint4*)&qsum[rec + 4*g] = w0;
        }
    } // lq
}

// ---------------- kernel B: head, dual-sample --------------------------------

__global__ __launch_bounds__(256, 2) void resnet_part2(
    const float* __restrict__ VA, const float* __restrict__ wsf,
    const unsigned* __restrict__ qsum, const float* __restrict__ bvs,
    float* __restrict__ out, int n_total)
{
    __shared__ uint4 lw2[24*64];
    __shared__ alignas(16) float fbB[320];

    {
        const uint4* src = (const uint4*)wsf;
        for (int i = threadIdx.x; i < 24*64; i += blockDim.x) lw2[i] = src[26*64 + i];
        uint4* fb4 = (uint4*)fbB;
        for (int i = threadIdx.x; i < 80; i += blockDim.x) fb4[i] = src[3224 + i];
    }
    __syncthreads();

    const int l  = threadIdx.x & 63;
    const int wv = threadIdx.x >> 6;
    const int c  = l & 15, g = l >> 4;
    const int base = blockIdx.x*128 + wv*32;
    const int s0 = base + c, s1 = base + 16 + c;
    const int sl0 = (s0 < n_total) ? s0 : (n_total-1);
    const int sl1 = (s1 < n_total) ? s1 : (n_total-1);
    const bool g0 = (g==0);

    const uint4* lwl = lw2 + l;
    #define LDB(T) __builtin_bit_cast(f16x8, lwl[((T)-26)*64])

    uint4 Bva[2];
    Bva[0].x=0; Bva[0].y=0; Bva[0].z=0; Bva[0].w=0;
    Bva[1] = Bva[0];
    if (g0) {
        Bva[0].x = pk(1.0f, VA[2*sl0]); Bva[0].y = pk(VA[2*sl0+1], 0.0f);
        Bva[1].x = pk(1.0f, VA[2*sl1]); Bva[1].y = pk(VA[2*sl1+1], 0.0f);
    }

    const f32x4 z4 = {0.f,0.f,0.f,0.f};
    float out_acc[2] = {0.0f, 0.0f};

    #pragma unroll 1
    for (int lq = 0; lq < 3; ++lq) {
        uint4 BQ[2];
        BQ[0] = *(const uint4*)&qsum[(lq*n_total + sl0)*16 + 4*g];
        BQ[1] = *(const uint4*)&qsum[(lq*n_total + sl1)*16 + 4*g];

        f32x4 uacc[2][4], w[2][4];
        #pragma unroll
        for (int mt=0; mt<4; ++mt) {
            const f16x8 A0 = LDB(26+2*mt), A1 = LDB(27+2*mt);
            #pragma unroll
            for (int u = 0; u < 2; ++u) {
                f32x4 acc = MFMA(A0, BQ[u], z4);
                uacc[u][mt] = MFMA(A1, Bva[u], acc);
            }
        }
        uint4 B0[2], B1[2];
        #pragma unroll
        for (int u = 0; u < 2; ++u) {
            { f32x4 t0=silu4(uacc[u][0]), t1=silu4(uacc[u][1]); PACKB(B0[u], t0, t1); }
            { f32x4 t0=silu4(uacc[u][2]), t1=silu4(uacc[u][3]); PACKB(B1[u], t0, t1); }
        }
        #pragma unroll
        for (int mt=0; mt<4; ++mt) {
            const f16x8 A0 = LDB(34+2*mt), A1 = LDB(35+2*mt);
            const f32x4 bb = *(const f32x4*)&fbB[16*mt + 4*g];
            #pragma unroll
            for (int u = 0; u < 2; ++u) {
                f32x4 acc = MFMA(A0, B0[u], uacc[u][mt]);   // v1: C = u0
                acc = MFMA(A1, B1[u], acc);
                w[u][mt] = acc + bb;
            }
        }
        #pragma unroll
        for (int u = 0; u < 2; ++u) {
            { f32x4 t0=silu4(w[u][0]), t1=silu4(w[u][1]); PACKB(B0[u], t0, t1); }
            { f32x4 t0=silu4(w[u][2]), t1=silu4(w[u][3]); PACKB(B1[u], t0, t1); }
        }
        #pragma unroll
        for (int mt=0; mt<4; ++mt) {
            const f16x8 A0 = LDB(42+2*mt), A1 = LDB(43+2*mt);
            const f32x4 bb = *(const f32x4*)&fbB[64 + 16*mt + 4*g];
            #pragma unroll
            for (int u = 0; u < 2; ++u) {
                f32x4 acc = MFMA(A0, B0[u], uacc[u][mt]);   // v2: C = u0
                acc = MFMA(A1, B1[u], acc);
                w[u][mt] = acc + bb;
            }
        }
        #pragma unroll
        for (int mt=0; mt<4; ++mt) {
            const f32x4 wvs = *(const f32x4*)&fbB[128 + 64*lq + 16*mt + 4*g];
            #pragma unroll
            for (int u = 0; u < 2; ++u) {
                out_acc[u] += wvs.x*silu_f(w[u][mt].x) + wvs.y*silu_f(w[u][mt].y)
                            + wvs.z*silu_f(w[u][mt].z) + wvs.w*silu_f(w[u][mt].w);
            }
        }
    } // lq

    #pragma unroll
    for (int u = 0; u < 2; ++u) {
        out_acc[u] += __shfl_xor(out_acc[u], 16, 64);
        out_acc[u] += __shfl_xor(out_acc[u], 32, 64);
    }
    if (g0) {
        const float b0 = bvs[0];
        if (s0 < n_total) out[s0] = out_acc[0] + b0;
        if (s1 < n_total) out[s1] = out_acc[1] + b0;
    }
}

extern "C" void kernel_launch(void* const* d_in, const int* in_sizes, int n_in,
                              void* d_out, int out_size, void* d_ws, size_t ws_size,
                              hipStream_t stream)
{
    (void)n_in; (void)ws_size; (void)out_size;
    const float* P   = (const float*)d_in[1];
    const float* DA  = (const float*)d_in[2];
    const float* QA  = (const float*)d_in[3];
    const float* VA  = (const float*)d_in[4];
    const float* Wtd = (const float*)d_in[5];   const float* btd = (const float*)d_in[6];
    const float* Wdb = (const float*)d_in[7];   const float* bdb = (const float*)d_in[8];
    const float* Wdr1= (const float*)d_in[9];   const float* bdr1= (const float*)d_in[10];
    const float* Wdr2= (const float*)d_in[11];  const float* bdr2= (const float*)d_in[12];
    const float* Wtq = (const float*)d_in[13];  const float* btq = (const float*)d_in[14];
    const float* Wqb = (const float*)d_in[15];  const float* bqb = (const float*)d_in[16];
    const float* Wqr1= (const float*)d_in[17];  const float* bqr1= (const float*)d_in[18];
    const float* Wqr2= (const float*)d_in[19];  const float* bqr2= (const float*)d_in[20];
    const float* Wtv = (const float*)d_in[21];  const float* btv = (const float*)d_in[22];
    const float* Wv1 = (const float*)d_in[23];  const float* bv1 = (const float*)d_in[24];
    const float* Wv2 = (const float*)d_in[25];  const float* bv2 = (const float*)d_in[26];
    const float* Wvs = (const float*)d_in[27];  const float* bvs = (const float*)d_in[28];
    float* out = (float*)d_out;

    const int n_total = in_sizes[1] / 48;   // p is [N,4,12]
    float* wsf = (float*)d_ws;
    unsigned* qsum = (unsigned*)(wsf + QSUM_DW);

    precompute<<<dim3(64), dim3(256), 0, stream>>>(
        Wtd, btd, Wdb, bdb, Wdr1, bdr1, Wdr2, bdr2,
        Wtq, btq, Wqb, bqb, Wqr1, bqr1, Wqr2, bqr2,
        Wtv, btv, Wv1, bv1, Wv2, bv2, Wvs, wsf);

    const int grid1 = (n_total + 63) / 64;
    resnet_part1<<<dim3(grid1), dim3(256), 0, stream>>>(
        P, DA, QA, wsf, qsum, n_total);
    const int grid2 = (n_total + 127) / 128;
    resnet_part2<<<dim3(grid2), dim3(256), 0, stream>>>(
        VA, wsf, qsum, bvs, out, n_total);
}

// Round 20
// 205.095 us; speedup vs baseline: 1.2289x; 1.0029x over previous
//
#include <hip/hip_runtime.h>

// Round 20: part1 input-load vectorization (P rows as aligned float4, DA as
// float2 -- was ~20 scalar 192B-strided loads per lq) + minimal-sequence silu
// (exp2-based, 5 instrs). Everything else = round 19 (best, 205.7us):
// part1 (256,2)/112VGPR spill-free, dual-sample part2 (256,2), PACKB sigma.

typedef _Float16 f16x8 __attribute__((ext_vector_type(8)));
typedef float f32x4 __attribute__((ext_vector_type(4)));
typedef __fp16 fp16x2 __attribute__((ext_vector_type(2)));

#define TILES 50
#define WS_BIAS    12800
#define NBIAS      416
#define QSUM_DW    13216          // dword offset of qsum region in ws

// sigma: B k-slot -> producer channel (within a 32-channel D-tile-pair)
#define CIN(k) (16*(((k)>>2)&1) + 4*((k)>>3) + ((k)&3))

__device__ __forceinline__ float silu_f(float x){
#if __has_builtin(__builtin_amdgcn_exp2f)
    float e = __builtin_amdgcn_exp2f(-1.44269504f * x);
#else
    float e = __expf(-x);
#endif
    return x * __builtin_amdgcn_rcpf(1.0f + e);
}
__device__ __forceinline__ f32x4 silu4(f32x4 v){
    f32x4 r; r.x=silu_f(v.x); r.y=silu_f(v.y); r.z=silu_f(v.z); r.w=silu_f(v.w);
    return r;
}
__device__ __forceinline__ unsigned pk(float a, float b){
    fp16x2 h = __builtin_amdgcn_cvt_pkrtz(a, b);
    return __builtin_bit_cast(unsigned, h);
}
#define PACKB(RES, T0, T1) {                                                   \
    (RES).x = pk((T0).x,(T0).y); (RES).y = pk((T0).z,(T0).w);                  \
    (RES).z = pk((T1).x,(T1).y); (RES).w = pk((T1).z,(T1).w); }

// ---------------- precompute: composed weights -> A-frag order ----------------

__device__ float l1_Ad0(const float* Wdb, const float* Wtd, int c, int k){
    int h = k>>2, jr = k&3; float a = 0.f;
    for (int i=0;i<32;++i) a += Wdb[64*c+2*i+h]*Wtd[4*i+jr];
    return a;
}
__device__ float l1_AB(const float* Wdb,const float* bdb,const float* btd,int c){
    float b = bdb[c];
    for (int i=0;i<32;++i) b += (Wdb[64*c+2*i]+Wdb[64*c+2*i+1])*btd[i];
    return b;
}
__device__ float l1_M(const float* Wdr,const float* Wtd,int c,int k){
    int h=k>>2, jr=k&3; float a=0.f;
    for(int i=0;i<32;++i) a += Wdr[96*c+3*i+h]*Wtd[4*i+jr];
    return a;
}
__device__ float l1_MB(const float* Wdr,const float* bdr,const float* btd,int c){
    float b = bdr[c];
    for(int i=0;i<32;++i) b += (Wdr[96*c+3*i]+Wdr[96*c+3*i+1])*btd[i];
    return b;
}
__device__ float qn_Q(const float* Wqb, const float* Wtq, int c, int kg){
    int z=kg>>5, kk=kg&31; float a=0.f;
    for(int i=0;i<32;++i) a += Wqb[64*c+2*i+z]*Wtq[32*i+kk];
    return a;
}
__device__ float qn_N(const float* Wqr, const float* Wtq, int c, int kg){
    int z=kg>>5, kk=kg&31; float a=0.f;
    for(int i=0;i<32;++i) a += Wqr[96*c+3*i+z]*Wtq[32*i+kk];
    return a;
}

__global__ void precompute(
    const float* __restrict__ Wtd, const float* __restrict__ btd,
    const float* __restrict__ Wdb, const float* __restrict__ bdb,
    const float* __restrict__ Wdr1, const float* __restrict__ bdr1,
    const float* __restrict__ Wdr2, const float* __restrict__ bdr2,
    const float* __restrict__ Wtq, const float* __restrict__ btq,
    const float* __restrict__ Wqb, const float* __restrict__ bqb,
    const float* __restrict__ Wqr1, const float* __restrict__ bqr1,
    const float* __restrict__ Wqr2, const float* __restrict__ bqr2,
    const float* __restrict__ Wtv, const float* __restrict__ btv,
    const float* __restrict__ Wv1, const float* __restrict__ bv1,
    const float* __restrict__ Wv2, const float* __restrict__ bv2,
    const float* __restrict__ Wvs,
    float* __restrict__ wsf)
{
    const int tid = blockIdx.x*blockDim.x + threadIdx.x;
    const int stride = gridDim.x*blockDim.x;

    for (int it = tid; it < TILES*64; it += stride) {
        const int tile = it >> 6, lane = it & 63;
        const int m = lane & 15, g = lane >> 4;
        float v[8];
        #pragma unroll
        for (int j = 0; j < 8; ++j) {
            const int k = 8*g + j;
            float val = 0.f;
            if (tile < 6) {
                // layer1: B is raw-input Bxi -- NO sigma
                const int r = 16*tile + m;
                if (r < 32) {
                    if (r < 30) {
                        if (k < 8)      val = l1_Ad0(Wdb, Wtd, r, k);
                        else if (k==8)  val = l1_AB(Wdb, bdb, btd, r);
                    } else if (r == 30) val = (k==9)  ? 1.f : 0.f;
                    else                val = (k==10) ? 1.f : 0.f;
                } else {
                    const float* Wdr = (r<64)? Wdr1 : Wdr2;
                    const float* bdr = (r<64)? bdr1 : bdr2;
                    const int c = (r<64)? r-32 : r-64;
                    if (k < 8) {
                        val = l1_M(Wdr, Wtd, c, k);
                        if (c < 30) val += l1_Ad0(Wdb, Wtd, c, k);
                    } else if (k == 8) {
                        val = l1_MB(Wdr, bdr, btd, c);
                        if (c < 30) val += l1_AB(Wdb, bdb, btd, c);
                    } else if (k == 9)  val = (c==30)? 1.f : 0.f;
                    else if (k == 10)   val = (c==31)? 1.f : 0.f;
                }
            } else if (tile < 8)  { val = Wdr1[96*(16*(tile-6)+m) + 3*CIN(k) + 2]; }
            else if (tile < 10)   { val = Wdr2[96*(16*(tile-8)+m) + 3*CIN(k) + 2]; }
            else if (tile < 22) {
                const int tt = tile-10, r = 16*(tt>>1)+m, kg = 32*(tt&1)+CIN(k);
                if (r < 32) { if (r < 30) val = qn_Q(Wqb, Wtq, r, kg); }
                else {
                    const float* Wqr = (r<64)? Wqr1 : Wqr2;
                    const int c = (r<64)? r-32 : r-64;
                    val = qn_N(Wqr, Wtq, c, kg);
                    if (c < 30) val += qn_Q(Wqb, Wtq, c, kg);
                }
            }
            else if (tile < 24)  { val = Wqr1[96*(16*(tile-22)+m) + 3*CIN(k) + 2]; }
            else if (tile < 26)  { val = Wqr2[96*(16*(tile-24)+m) + 3*CIN(k) + 2]; }
            else if (tile < 34) {
                const int tt = tile-26, r = 16*(tt>>1)+m;
                if ((tt&1)==0) val = 0.25f*Wtv[34*r + CIN(k)];
                else {
                    if (k==0) val = btv[r];
                    else if (k==1) val = Wtv[34*r+32];
                    else if (k==2) val = Wtv[34*r+33];
                }
            }
            else if (tile < 42) { const int tt=tile-34; val = Wv1[64*(16*(tt>>1)+m) + 32*(tt&1) + CIN(k)]; }
            else                { const int tt=tile-42; val = Wv2[64*(16*(tt>>1)+m) + 32*(tt&1) + CIN(k)]; }
            v[j] = val;
        }
        unsigned* wd = (unsigned*)wsf;
        const int base = tile*256 + lane*4;
        wd[base+0] = pk(v[0],v[1]);
        wd[base+1] = pk(v[2],v[3]);
        wd[base+2] = pk(v[4],v[5]);
        wd[base+3] = pk(v[6],v[7]);
    }

    for (int r = tid; r < NBIAS; r += stride) {
        float val = 0.f;
        if (r < 96) {
            if (r < 30) {
                float b = bqb[r];
                for (int i=0;i<32;++i) b += (Wqb[64*r+2*i]+Wqb[64*r+2*i+1])*btq[i];
                val = b;
            } else if (r >= 32) {
                const float* Wqr = (r<64)? Wqr1 : Wqr2;
                const float* bqr = (r<64)? bqr1 : bqr2;
                const int c = (r<64)? r-32 : r-64;
                float b = bqr[c];
                for (int i=0;i<32;++i) b += (Wqr[96*c+3*i]+Wqr[96*c+3*i+1])*btq[i];
                if (c < 30) {
                    float qb = bqb[c];
                    for (int i=0;i<32;++i) qb += (Wqb[64*c+2*i]+Wqb[64*c+2*i+1])*btq[i];
                    b += qb;
                }
                val = b;
            }
        }
        else if (r < 160) val = bv1[r-96];
        else if (r < 224) val = bv2[r-160];
        else { const int idx = r-224, lq = idx>>6, row = idx&63; val = Wvs[3*row + lq]; }
        wsf[WS_BIAS + r] = val;
    }
}

// ---------------- kernel A: d-chain + q-layer -> qsum (packed fp16) ----------

__global__ __launch_bounds__(256, 2) void resnet_part1(
    const float* __restrict__ P,  const float* __restrict__ DA,
    const float* __restrict__ QA, const float* __restrict__ wsf,
    unsigned* __restrict__ qsum, int n_total)
{
    __shared__ uint4 lw[26*64];
    __shared__ alignas(16) float fbA[96];

    {
        const uint4* src = (const uint4*)wsf;
        for (int i = threadIdx.x; i < 26*64; i += blockDim.x) lw[i] = src[i];
        uint4* fb4 = (uint4*)fbA;
        for (int i = threadIdx.x; i < 24; i += blockDim.x) fb4[i] = src[3200 + i];
    }
    __syncthreads();

    const int l  = threadIdx.x & 63;
    const int wv = threadIdx.x >> 6;
    const int c  = l & 15, g = l >> 4;
    const int s  = blockIdx.x*64 + wv*16 + c;
    const int sl = (s < n_total) ? s : (n_total-1);
    const bool g0 = (g==0), g1 = (g==1);

    const uint4* lwl = lw + l;
    #define LDA(T) __builtin_bit_cast(f16x8, lwl[(T)*64])
    #define MFMA(A,B,C) __builtin_amdgcn_mfma_f32_16x16x32_f16((A), __builtin_bit_cast(f16x8,(B)), (C), 0, 0, 0)

    const unsigned me = g0 ? 0x80000000u : 0u;   // eta sign slots
    const unsigned mp = g0 ? 0x00008000u : 0u;   // phi sign slots

    const f32x4 z4 = {0.f,0.f,0.f,0.f};

    #pragma unroll 1
    for (int lq = 0; lq < 3; ++lq) {
        // vectorized input loads: 4x float4 (P rows) + 2x float2 (DA) + 2 scalars
        uint4 xb[2];
        {
            const float4 r0 = *(const float4*)&P[48*sl      + 4*lq];
            const float4 r1 = *(const float4*)&P[48*sl + 12 + 4*lq];
            const float4 r2 = *(const float4*)&P[48*sl + 24 + 4*lq];
            const float4 r3 = *(const float4*)&P[48*sl + 36 + 4*lq];
            const float2 dA = *(const float2*)&DA[12*sl     + 2*lq];
            const float2 dB = *(const float2*)&DA[12*sl + 6 + 2*lq];
            float w2[4];
            {
                float y0 = r2.x + 1.0f; y0 -= 2.0f*floorf(y0*0.5f); w2[0] = y0 - 1.0f;
                float y1 = r2.y + 1.0f; y1 -= 2.0f*floorf(y1*0.5f); w2[1] = y1 - 1.0f;
                float y2 = r2.z + 1.0f; y2 -= 2.0f*floorf(y2*0.5f); w2[2] = y2 - 1.0f;
                float y3 = r2.w + 1.0f; y3 -= 2.0f*floorf(y3*0.5f); w2[3] = y3 - 1.0f;
            }
            const float p0[4] = {r0.x, r0.y, r0.z, r0.w};
            const float p1[4] = {r1.x, r1.y, r1.z, r1.w};
            const float p3[4] = {r3.x, r3.y, r3.z, r3.w};
            const float dav0[2] = {dA.x, dA.y};
            const float dav1[2] = {dB.x, dB.y};
            #pragma unroll
            for (int t = 0; t < 2; ++t) {
                uint4 xv; xv.x=0; xv.y=0; xv.z=0; xv.w=0;
                if (g0) {
                    xv.x = pk(p0[2*t],   p1[2*t]);
                    xv.y = pk(w2[2*t],   p3[2*t]);
                    xv.z = pk(p0[2*t+1], p1[2*t+1]);
                    xv.w = pk(w2[2*t+1], p3[2*t+1]);
                } else if (g1) {
                    xv.x = pk(1.0f, dav0[t]); xv.y = pk(dav1[t], 0.0f);
                }
                xb[t] = xv;
            }
        }
        const float qa30m = (g==3) ? QA[6*sl + lq]     : 0.0f;
        const float qa31m = (g==3) ? QA[6*sl + 3 + lq] : 0.0f;

        f32x4 qav0 = z4, qav1 = z4;

        #pragma unroll 1
        for (int var = 0; var < 4; ++var) {
            const unsigned fe = (var>=2)? me : 0u;
            const unsigned fp = (var==1||var==2)? mp : 0u;

            uint4 Bs[2];
            #pragma unroll
            for (int t = 0; t < 2; ++t) {
                uint4 Bxi;
                Bxi.x = xb[t].x ^ fe; Bxi.y = xb[t].y ^ fp;
                Bxi.z = xb[t].z ^ fe; Bxi.w = xb[t].w ^ fp;

                f32x4 a0 = MFMA(LDA(0), Bxi, z4);
                f32x4 a1 = MFMA(LDA(1), Bxi, z4);
                f32x4 a2 = MFMA(LDA(2), Bxi, z4);
                f32x4 a3 = MFMA(LDA(3), Bxi, z4);
                f32x4 a4 = MFMA(LDA(4), Bxi, z4);
                f32x4 a5 = MFMA(LDA(5), Bxi, z4);

                uint4 Bt;
                { f32x4 s0=silu4(a0), s1=silu4(a1); PACKB(Bt, s0, s1); }
                a2 = MFMA(LDA(6), Bt, a2);
                a3 = MFMA(LDA(7), Bt, a3);
                { f32x4 s0=silu4(a2), s1=silu4(a3); PACKB(Bt, s0, s1); }
                a4 = MFMA(LDA(8), Bt, a4);
                a5 = MFMA(LDA(9), Bt, a5);
                { f32x4 s0=silu4(a4), s1=silu4(a5); PACKB(Bs[t], s0, s1); }
            }

            f32x4 q[6];
            #pragma unroll
            for (int mt=0; mt<6; ++mt) {
                f32x4 acc = MFMA(LDA(10+2*mt), Bs[0], *(const f32x4*)&fbA[16*mt + 4*g]);
                q[mt] = MFMA(LDA(10+2*mt+1), Bs[1], acc);
            }
            q[1].z += qa30m; q[1].w += qa31m;
            q[3].z += qa30m; q[3].w += qa31m;
            q[5].z += qa30m; q[5].w += qa31m;

            uint4 Bq;
            { f32x4 s0=silu4(q[0]), s1=silu4(q[1]); PACKB(Bq, s0, s1); }
            q[2] = MFMA(LDA(22), Bq, q[2]);
            q[3] = MFMA(LDA(23), Bq, q[3]);
            { f32x4 s0=silu4(q[2]), s1=silu4(q[3]); PACKB(Bq, s0, s1); }
            q[4] = MFMA(LDA(24), Bq, q[4]);
            q[5] = MFMA(LDA(25), Bq, q[5]);
            qav0 += silu4(q[4]);
            qav1 += silu4(q[5]);
        } // var

        // qsum: lane(c,g) holds ks 8g..8g+7 directly -> one uint4 store
        if (s < n_total) {
            const int rec = (lq*n_total + sl)*16;
            uint4 w0; PACKB(w0, qav0, qav1);
            *(uint4*)&qsum[rec + 4*g] = w0;
        }
    } // lq
}

// ---------------- kernel B: head, dual-sample --------------------------------

__global__ __launch_bounds__(256, 2) void resnet_part2(
    const float* __restrict__ VA, const float* __restrict__ wsf,
    const unsigned* __restrict__ qsum, const float* __restrict__ bvs,
    float* __restrict__ out, int n_total)
{
    __shared__ uint4 lw2[24*64];
    __shared__ alignas(16) float fbB[320];

    {
        const uint4* src = (const uint4*)wsf;
        for (int i = threadIdx.x; i < 24*64; i += blockDim.x) lw2[i] = src[26*64 + i];
        uint4* fb4 = (uint4*)fbB;
        for (int i = threadIdx.x; i < 80; i += blockDim.x) fb4[i] = src[3224 + i];
    }
    __syncthreads();

    const int l  = threadIdx.x & 63;
    const int wv = threadIdx.x >> 6;
    const int c  = l & 15, g = l >> 4;
    const int base = blockIdx.x*128 + wv*32;
    const int s0 = base + c, s1 = base + 16 + c;
    const int sl0 = (s0 < n_total) ? s0 : (n_total-1);
    const int sl1 = (s1 < n_total) ? s1 : (n_total-1);
    const bool g0 = (g==0);

    const uint4* lwl = lw2 + l;
    #define LDB(T) __builtin_bit_cast(f16x8, lwl[((T)-26)*64])

    uint4 Bva[2];
    Bva[0].x=0; Bva[0].y=0; Bva[0].z=0; Bva[0].w=0;
    Bva[1] = Bva[0];
    if (g0) {
        Bva[0].x = pk(1.0f, VA[2*sl0]); Bva[0].y = pk(VA[2*sl0+1], 0.0f);
        Bva[1].x = pk(1.0f, VA[2*sl1]); Bva[1].y = pk(VA[2*sl1+1], 0.0f);
    }

    const f32x4 z4 = {0.f,0.f,0.f,0.f};
    float out_acc[2] = {0.0f, 0.0f};

    #pragma unroll 1
    for (int lq = 0; lq < 3; ++lq) {
        uint4 BQ[2];
        BQ[0] = *(const uint4*)&qsum[(lq*n_total + sl0)*16 + 4*g];
        BQ[1] = *(const uint4*)&qsum[(lq*n_total + sl1)*16 + 4*g];

        f32x4 uacc[2][4], w[2][4];
        #pragma unroll
        for (int mt=0; mt<4; ++mt) {
            const f16x8 A0 = LDB(26+2*mt), A1 = LDB(27+2*mt);
            #pragma unroll
            for (int u = 0; u < 2; ++u) {
                f32x4 acc = MFMA(A0, BQ[u], z4);
                uacc[u][mt] = MFMA(A1, Bva[u], acc);
            }
        }
        uint4 B0[2], B1[2];
        #pragma unroll
        for (int u = 0; u < 2; ++u) {
            { f32x4 t0=silu4(uacc[u][0]), t1=silu4(uacc[u][1]); PACKB(B0[u], t0, t1); }
            { f32x4 t0=silu4(uacc[u][2]), t1=silu4(uacc[u][3]); PACKB(B1[u], t0, t1); }
        }
        #pragma unroll
        for (int mt=0; mt<4; ++mt) {
            const f16x8 A0 = LDB(34+2*mt), A1 = LDB(35+2*mt);
            const f32x4 bb = *(const f32x4*)&fbB[16*mt + 4*g];
            #pragma unroll
            for (int u = 0; u < 2; ++u) {
                f32x4 acc = MFMA(A0, B0[u], uacc[u][mt]);   // v1: C = u0
                acc = MFMA(A1, B1[u], acc);
                w[u][mt] = acc + bb;
            }
        }
        #pragma unroll
        for (int u = 0; u < 2; ++u) {
            { f32x4 t0=silu4(w[u][0]), t1=silu4(w[u][1]); PACKB(B0[u], t0, t1); }
            { f32x4 t0=silu4(w[u][2]), t1=silu4(w[u][3]); PACKB(B1[u], t0, t1); }
        }
        #pragma unroll
        for (int mt=0; mt<4; ++mt) {
            const f16x8 A0 = LDB(42+2*mt), A1 = LDB(43+2*mt);
            const f32x4 bb = *(const f32x4*)&fbB[64 + 16*mt + 4*g];
            #pragma unroll
            for (int u = 0; u < 2; ++u) {
                f32x4 acc = MFMA(A0, B0[u], uacc[u][mt]);   // v2: C = u0
                acc = MFMA(A1, B1[u], acc);
                w[u][mt] = acc + bb;
            }
        }
        #pragma unroll
        for (int mt=0; mt<4; ++mt) {
            const f32x4 wvs = *(const f32x4*)&fbB[128 + 64*lq + 16*mt + 4*g];
            #pragma unroll
            for (int u = 0; u < 2; ++u) {
                out_acc[u] += wvs.x*silu_f(w[u][mt].x) + wvs.y*silu_f(w[u][mt].y)
                            + wvs.z*silu_f(w[u][mt].z) + wvs.w*silu_f(w[u][mt].w);
            }
        }
    } // lq

    #pragma unroll
    for (int u = 0; u < 2; ++u) {
        out_acc[u] += __shfl_xor(out_acc[u], 16, 64);
        out_acc[u] += __shfl_xor(out_acc[u], 32, 64);
    }
    if (g0) {
        const float b0 = bvs[0];
        if (s0 < n_total) out[s0] = out_acc[0] + b0;
        if (s1 < n_total) out[s1] = out_acc[1] + b0;
    }
}

extern "C" void kernel_launch(void* const* d_in, const int* in_sizes, int n_in,
                              void* d_out, int out_size, void* d_ws, size_t ws_size,
                              hipStream_t stream)
{
    (void)n_in; (void)ws_size; (void)out_size;
    const float* P   = (const float*)d_in[1];
    const float* DA  = (const float*)d_in[2];
    const float* QA  = (const float*)d_in[3];
    const float* VA  = (const float*)d_in[4];
    const float* Wtd = (const float*)d_in[5];   const float* btd = (const float*)d_in[6];
    const float* Wdb = (const float*)d_in[7];   const float* bdb = (const float*)d_in[8];
    const float* Wdr1= (const float*)d_in[9];   const float* bdr1= (const float*)d_in[10];
    const float* Wdr2= (const float*)d_in[11];  const float* bdr2= (const float*)d_in[12];
    const float* Wtq = (const float*)d_in[13];  const float* btq = (const float*)d_in[14];
    const float* Wqb = (const float*)d_in[15];  const float* bqb = (const float*)d_in[16];
    const float* Wqr1= (const float*)d_in[17];  const float* bqr1= (const float*)d_in[18];
    const float* Wqr2= (const float*)d_in[19];  const float* bqr2= (const float*)d_in[20];
    const float* Wtv = (const float*)d_in[21];  const float* btv = (const float*)d_in[22];
    const float* Wv1 = (const float*)d_in[23];  const float* bv1 = (const float*)d_in[24];
    const float* Wv2 = (const float*)d_in[25];  const float* bv2 = (const float*)d_in[26];
    const float* Wvs = (const float*)d_in[27];  const float* bvs = (const float*)d_in[28];
    float* out = (float*)d_out;

    const int n_total = in_sizes[1] / 48;   // p is [N,4,12]
    float* wsf = (float*)d_ws;
    unsigned* qsum = (unsigned*)(wsf + QSUM_DW);

    precompute<<<dim3(64), dim3(256), 0, stream>>>(
        Wtd, btd, Wdb, bdb, Wdr1, bdr1, Wdr2, bdr2,
        Wtq, btq, Wqb, bqb, Wqr1, bqr1, Wqr2, bqr2,
        Wtv, btv, Wv1, bv1, Wv2, bv2, Wvs, wsf);

    const int grid1 = (n_total + 63) / 64;
    resnet_part1<<<dim3(grid1), dim3(256), 0, stream>>>(
        P, DA, QA, wsf, qsum, n_total);
    const int grid2 = (n_total + 127) / 128;
    resnet_part2<<<dim3(grid2), dim3(256), 0, stream>>>(
        VA, wsf, qsum, bvs, out, n_total);
}